// Round 1
// baseline (8042.661 us; speedup 1.0000x reference)
//
#include <hip/hip_runtime.h>

typedef unsigned short u16;
typedef __attribute__((ext_vector_type(8))) short short8;
typedef __attribute__((ext_vector_type(4))) float f32x4;

#define NGRID 256
#define BDIM 512

__device__ inline u16 f2bf(float f){
  unsigned u = __float_as_uint(f);
  return (u16)((u + 0x7FFFu + ((u>>16)&1u)) >> 16);
}
__device__ inline float bf2f(u16 h){ return __uint_as_float(((unsigned)h)<<16); }
__device__ inline void splitw(float f, u16 &hi, u16 &lo){
  hi = f2bf(f);
  float r = f - bf2f(hi);
  lo = f2bf(r);
}

// W[k][n] (1024x1024 row-major) -> Wth/Wtl[n][k] bf16 hi/lo, tiled transpose.
__global__ __launch_bounds__(256) void prep_weights(const float* __restrict__ W,
                                                    u16* __restrict__ Wth, u16* __restrict__ Wtl){
  __shared__ float tile[32][33];
  int n0 = blockIdx.x*32, k0 = blockIdx.y*32;
  int tx = threadIdx.x & 31, ty = threadIdx.x >> 5;  // 32 x 8
  #pragma unroll
  for (int j=0;j<4;++j)
    tile[ty+8*j][tx] = W[(k0+ty+8*j)*1024 + n0 + tx];
  __syncthreads();
  #pragma unroll
  for (int j=0;j<4;++j){
    int nl = ty + 8*j;
    float f = tile[tx][nl];
    u16 hi, lo; splitw(f, hi, lo);
    Wth[(size_t)(n0+nl)*1024 + k0 + tx] = hi;
    Wtl[(size_t)(n0+nl)*1024 + k0 + tx] = lo;
  }
}

__global__ __launch_bounds__(256) void init_z(const float* __restrict__ zi, float* __restrict__ z,
                                              u16* __restrict__ zh, u16* __restrict__ zl){
  int i = blockIdx.x*256 + threadIdx.x;
  float f = zi[i];
  z[i] = f;
  u16 h,l; splitw(f,h,l);
  zh[i]=h; zl[i]=l;
}

// MODE 0: h = tanh(A@W1 + ti*wt + b1)        (writes h hi/lo)
// MODE 1+s: k = A@W2 + b2, fused RK4 stage-s update
template<int MODE>
__global__ __launch_bounds__(512) void fused_gemm(
    const u16* __restrict__ Ahi, const u16* __restrict__ Alo,   // [512][1024] bf16 hi/lo
    const u16* __restrict__ Wth, const u16* __restrict__ Wtl,   // [1024][1024] transposed bf16 hi/lo
    const float* __restrict__ bias, const float* __restrict__ wtv,
    const float* __restrict__ tvec, int step, int which,
    u16* __restrict__ OutHi, u16* __restrict__ OutLo,
    float* __restrict__ Zbuf, float* __restrict__ Zacc)
{
  int b = blockIdx.x;
  int cb = b & 31, g = b >> 5;                // 32 col-blocks (XCD-pinned) x 8 row-groups
  int wave = (int)threadIdx.x >> 6, lane = (int)threadIdx.x & 63;
  int rw = wave & 3, cf = wave >> 2;          // wave -> (row-frag, col-frag)
  int lr = lane & 15, ks = lane >> 4;

  int arow = g*64 + rw*16 + lr;
  int bcol = cb*32 + cf*16 + lr;

  const u16* pah = Ahi + (size_t)arow*1024 + ks*8;
  const u16* pal = Alo + (size_t)arow*1024 + ks*8;
  const u16* pbh = Wth + (size_t)bcol*1024 + ks*8;
  const u16* pbl = Wtl + (size_t)bcol*1024 + ks*8;

  f32x4 acc = {0.f,0.f,0.f,0.f};
  #pragma unroll 4
  for (int kc = 0; kc < 32; ++kc){
    short8 ah = *(const short8*)(pah + kc*32);
    short8 al = *(const short8*)(pal + kc*32);
    short8 bh = *(const short8*)(pbh + kc*32);
    short8 bl = *(const short8*)(pbl + kc*32);
    acc = __builtin_amdgcn_mfma_f32_16x16x32_bf16(ah, bh, acc, 0,0,0);
    acc = __builtin_amdgcn_mfma_f32_16x16x32_bf16(al, bh, acc, 0,0,0);
    acc = __builtin_amdgcn_mfma_f32_16x16x32_bf16(ah, bl, acc, 0,0,0);
  }

  float t0 = tvec[step], t1 = tvec[step+1];
  float dt = t1 - t0, half = 0.5f*dt;
  int colg = bcol;
  int rowb = g*64 + rw*16 + ks*4;             // C/D: col=lane&15, row=(lane>>4)*4+i  [m89]

  if constexpr (MODE == 0){
    float ti = (which == 0) ? t0 : ((which == 3) ? t1 : (t0 + half));
    float bb = bias[colg] + ti * wtv[colg];
    #pragma unroll
    for (int i=0;i<4;++i){
      size_t idx = (size_t)(rowb + i)*1024 + colg;
      float hv = tanhf(acc[i] + bb);
      u16 h,l; splitw(hv,h,l);
      OutHi[idx] = h; OutLo[idx] = l;
    }
  } else {
    constexpr int S = MODE - 1;
    float bb = bias[colg];
    float dt6 = dt*(1.0f/6.0f), dt3 = dt*(1.0f/3.0f);
    #pragma unroll
    for (int i=0;i<4;++i){
      size_t idx = (size_t)(rowb + i)*1024 + colg;
      float kv = acc[i] + bb;
      if constexpr (S == 0){
        float zv = Zbuf[idx];
        float zm = zv + half*kv;
        u16 h,l; splitw(zm,h,l); OutHi[idx]=h; OutLo[idx]=l;
        Zacc[idx] = zv + dt6*kv;
      } else if constexpr (S == 1){
        float zv = Zbuf[idx];
        float zm = zv + half*kv;
        u16 h,l; splitw(zm,h,l); OutHi[idx]=h; OutLo[idx]=l;
        Zacc[idx] += dt3*kv;
      } else if constexpr (S == 2){
        float zv = Zbuf[idx];
        float zm = zv + dt*kv;
        u16 h,l; splitw(zm,h,l); OutHi[idx]=h; OutLo[idx]=l;
        Zacc[idx] += dt3*kv;
      } else {
        float zn = Zacc[idx] + dt6*kv;
        Zbuf[idx] = zn;                        // z (== d_out)
        u16 h,l; splitw(zn,h,l); OutHi[idx]=h; OutLo[idx]=l;  // z splits for next step
      }
    }
  }
}

extern "C" void kernel_launch(void* const* d_in, const int* in_sizes, int n_in,
                              void* d_out, int out_size, void* d_ws, size_t ws_size,
                              hipStream_t stream)
{
  (void)in_sizes; (void)n_in; (void)out_size; (void)ws_size;
  const float* z_init = (const float*)d_in[0];
  const float* tvec   = (const float*)d_in[1];
  const float* W1     = (const float*)d_in[2];
  const float* b1     = (const float*)d_in[3];
  const float* wt     = (const float*)d_in[4];
  const float* W2     = (const float*)d_in[5];
  const float* b2     = (const float*)d_in[6];
  float* z = (float*)d_out;                    // fp32 master state lives in d_out

  char* p = (char*)d_ws;
  const size_t EL = 512*1024;
  u16* zh  = (u16*)p; p += EL*2;
  u16* zl  = (u16*)p; p += EL*2;
  u16* zmh = (u16*)p; p += EL*2;
  u16* zml = (u16*)p; p += EL*2;
  u16* hh  = (u16*)p; p += EL*2;
  u16* hl  = (u16*)p; p += EL*2;
  float* zacc = (float*)p; p += EL*4;
  u16* W1h = (u16*)p; p += (size_t)1024*1024*2;
  u16* W1l = (u16*)p; p += (size_t)1024*1024*2;
  u16* W2h = (u16*)p; p += (size_t)1024*1024*2;
  u16* W2l = (u16*)p; p += (size_t)1024*1024*2;

  prep_weights<<<dim3(32,32),256,0,stream>>>(W1, W1h, W1l);
  prep_weights<<<dim3(32,32),256,0,stream>>>(W2, W2h, W2l);
  init_z<<<2048,256,0,stream>>>(z_init, z, zh, zl);

  for (int step=0; step<32; ++step){
    for (int s=0; s<4; ++s){
      const u16* ah = (s==0)? zh : zmh;
      const u16* al = (s==0)? zl : zml;
      fused_gemm<0><<<NGRID,BDIM,0,stream>>>(ah, al, W1h, W1l, b1, wt, tvec, step, s,
                                             hh, hl, nullptr, nullptr);
      u16* oh = (s==3)? zh : zmh;
      u16* ol = (s==3)? zl : zml;
      switch (s){
        case 0: fused_gemm<1><<<NGRID,BDIM,0,stream>>>(hh, hl, W2h, W2l, b2, nullptr, tvec, step, s, oh, ol, z, zacc); break;
        case 1: fused_gemm<2><<<NGRID,BDIM,0,stream>>>(hh, hl, W2h, W2l, b2, nullptr, tvec, step, s, oh, ol, z, zacc); break;
        case 2: fused_gemm<3><<<NGRID,BDIM,0,stream>>>(hh, hl, W2h, W2l, b2, nullptr, tvec, step, s, oh, ol, z, zacc); break;
        case 3: fused_gemm<4><<<NGRID,BDIM,0,stream>>>(hh, hl, W2h, W2l, b2, nullptr, tvec, step, s, oh, ol, z, zacc); break;
      }
    }
  }
}

// Round 2
// 2625.721 us; speedup vs baseline: 3.0630x; 3.0630x over previous
//
#include <hip/hip_runtime.h>

typedef unsigned short u16;
typedef unsigned int u32;
typedef __attribute__((ext_vector_type(8))) short short8;
typedef __attribute__((ext_vector_type(4))) float f32x4;
typedef const __attribute__((address_space(1))) u32 gu32;
typedef __attribute__((address_space(3))) u32 lu32;

#define NGRID 256
#define BDIM 512

__device__ inline u16 f2bf(float f){
  unsigned u = __float_as_uint(f);
  return (u16)((u + 0x7FFFu + ((u>>16)&1u)) >> 16);
}
__device__ inline float bf2f(u16 h){ return __uint_as_float(((unsigned)h)<<16); }
__device__ inline void splitw(float f, u16 &hi, u16 &lo){
  hi = f2bf(f);
  lo = f2bf(f - bf2f(hi));
}
__device__ inline void gll16(const void* g, void* l){
  __builtin_amdgcn_global_load_lds((gu32*)g, (lu32*)l, 16, 0, 0);
}

// W[k][n] (1024x1024 row-major) -> Wth/Wtl[n][k] bf16 hi/lo, tiled transpose.
__global__ __launch_bounds__(256) void prep_weights(const float* __restrict__ W,
                                                    u16* __restrict__ Wth, u16* __restrict__ Wtl){
  __shared__ float tile[32][33];
  int n0 = blockIdx.x*32, k0 = blockIdx.y*32;
  int tx = threadIdx.x & 31, ty = threadIdx.x >> 5;  // 32 x 8
  #pragma unroll
  for (int j=0;j<4;++j)
    tile[ty+8*j][tx] = W[(k0+ty+8*j)*1024 + n0 + tx];
  __syncthreads();
  #pragma unroll
  for (int j=0;j<4;++j){
    int nl = ty + 8*j;
    float f = tile[tx][nl];
    u16 hi, lo; splitw(f, hi, lo);
    Wth[(size_t)(n0+nl)*1024 + k0 + tx] = hi;
    Wtl[(size_t)(n0+nl)*1024 + k0 + tx] = lo;
  }
}

__global__ __launch_bounds__(256) void init_z(const float* __restrict__ zi, float* __restrict__ z,
                                              u16* __restrict__ zh, u16* __restrict__ zl){
  int i = blockIdx.x*256 + threadIdx.x;
  float f = zi[i];
  z[i] = f;
  u16 h,l; splitw(f,h,l);
  zh[i]=h; zl[i]=l;
}

// Tile: BM=64 x BN=32, BK=128, 8 K-steps, double-buffered LDS staged via
// global_load_lds(16B) with XOR-swizzle (rule 21: linear LDS dest +
// inverse-swizzled global source + swizzled ds_read).
// LDS buffer layout (bytes): A_hi [0,16384) A_lo [16384,32768)
//                            B_hi [32768,40960) B_lo [40960,49152)
// MODE 0: h = tanh(A@W1 + ti*wt + b1)        (writes h hi/lo)
// MODE 1+s: k = A@W2 + b2, fused RK4 stage-s update
template<int MODE>
__global__ __launch_bounds__(512) void fused_gemm(
    const u16* __restrict__ Ahi, const u16* __restrict__ Alo,   // [512][1024]
    const u16* __restrict__ Wth, const u16* __restrict__ Wtl,   // [1024][1024] (n-major)
    const float* __restrict__ bias, const float* __restrict__ wtv,
    const float* __restrict__ tvec, int step, int which,
    u16* __restrict__ OutHi, u16* __restrict__ OutLo,
    float* __restrict__ Zbuf, float* __restrict__ Zacc)
{
  __shared__ u16 lds[2][24576];   // 2 x 48 KB
  const int tid  = threadIdx.x;
  const int b    = blockIdx.x;
  const int cb   = b & 31, g = b >> 5;         // col-block (XCD-pinned via b%8) x row-group
  const int wave = tid >> 6, lane = tid & 63;
  const int rw   = wave & 3, cf = wave >> 2;   // wave -> (row-frag, col-frag)
  const int lr   = lane & 15, ks = lane >> 4;

  // ---- staging address precompute (chunk = 16B = 8 u16 along k) ----
  const int ia1 = 512 + tid;
  const int r0 = tid >> 4,  c0 = tid & 15,  s0 = c0 ^ (r0 & 7);
  const int r1 = ia1 >> 4,  c1 = ia1 & 15,  s1 = c1 ^ (r1 & 7);
  const int rb = tid >> 4,  cbk = tid & 15, sb = cbk ^ (rb & 7);
  const size_t a0base = (size_t)(g*64 + r0)*1024 + s0*8;
  const size_t a1base = (size_t)(g*64 + r1)*1024 + s1*8;
  const size_t bbase  = (size_t)(cb*32 + rb)*1024 + sb*8;
  const int wb0 = (tid & ~63) * 16;            // wave-uniform LDS byte base
  const int wb1 = (512 + (tid & ~63)) * 16;
  const int wbb = (tid & ~63) * 16;

  // ---- fragment read offsets ----
  const int aoff = (rw*16 + lr) * 256;         // bytes: row * 128 u16 * 2
  const int boff = (cf*16 + lr) * 256;
  const int sw   = lr & 7;

  f32x4 acc0 = {0.f,0.f,0.f,0.f}, acc1 = {0.f,0.f,0.f,0.f};

  auto STAGE = [&](int bufi, int kt){
    char* L = (char*)&lds[bufi][0];
    size_t ko = (size_t)kt * 128;
    gll16(Ahi + a0base + ko, L + wb0);
    gll16(Ahi + a1base + ko, L + wb1);
    gll16(Alo + a0base + ko, L + 16384 + wb0);
    gll16(Alo + a1base + ko, L + 16384 + wb1);
    gll16(Wth + bbase + ko,  L + 32768 + wbb);
    gll16(Wtl + bbase + ko,  L + 40960 + wbb);
  };

  STAGE(0, 0);
  __syncthreads();                              // drains vmcnt -> buf0 ready
  #pragma unroll
  for (int kt = 0; kt < 8; ++kt){
    const int cur = kt & 1;
    if (kt < 7) STAGE(cur ^ 1, kt + 1);         // prefetch next tile (drained at barrier)
    const char* L = (const char*)&lds[cur][0];
    #pragma unroll
    for (int kc = 0; kc < 4; ++kc){
      const int ci = ((kc*4 + ks) ^ sw) * 16;
      short8 ah = *(const short8*)(L + aoff + ci);
      short8 al = *(const short8*)(L + 16384 + aoff + ci);
      short8 bh = *(const short8*)(L + 32768 + boff + ci);
      short8 bl = *(const short8*)(L + 40960 + boff + ci);
      if ((kc & 1) == 0){
        acc0 = __builtin_amdgcn_mfma_f32_16x16x32_bf16(ah, bh, acc0, 0,0,0);
        acc0 = __builtin_amdgcn_mfma_f32_16x16x32_bf16(al, bh, acc0, 0,0,0);
        acc0 = __builtin_amdgcn_mfma_f32_16x16x32_bf16(ah, bl, acc0, 0,0,0);
      } else {
        acc1 = __builtin_amdgcn_mfma_f32_16x16x32_bf16(ah, bh, acc1, 0,0,0);
        acc1 = __builtin_amdgcn_mfma_f32_16x16x32_bf16(al, bh, acc1, 0,0,0);
        acc1 = __builtin_amdgcn_mfma_f32_16x16x32_bf16(ah, bl, acc1, 0,0,0);
      }
    }
    __syncthreads();
  }
  const f32x4 acc = acc0 + acc1;

  // ---- epilogue (C/D: col=lane&15, row=(lane>>4)*4+i  [m89]) ----
  const float t0 = tvec[step], t1 = tvec[step+1];
  const float dt = t1 - t0, half = 0.5f*dt;
  const int colg = cb*32 + cf*16 + lr;
  const int rowb = g*64 + rw*16 + ks*4;

  if constexpr (MODE == 0){
    float ti = (which == 0) ? t0 : ((which == 3) ? t1 : (t0 + half));
    float bb = bias[colg] + ti * wtv[colg];
    #pragma unroll
    for (int i=0;i<4;++i){
      size_t idx = (size_t)(rowb + i)*1024 + colg;
      float hv = tanhf(acc[i] + bb);
      u16 h,l; splitw(hv,h,l);
      OutHi[idx] = h; OutLo[idx] = l;
    }
  } else {
    constexpr int S = MODE - 1;
    float bb = bias[colg];
    float dt6 = dt*(1.0f/6.0f), dt3 = dt*(1.0f/3.0f);
    #pragma unroll
    for (int i=0;i<4;++i){
      size_t idx = (size_t)(rowb + i)*1024 + colg;
      float kv = acc[i] + bb;
      if constexpr (S == 0){
        float zv = Zbuf[idx];
        float zm = zv + half*kv;
        u16 h,l; splitw(zm,h,l); OutHi[idx]=h; OutLo[idx]=l;
        Zacc[idx] = zv + dt6*kv;
      } else if constexpr (S == 1){
        float zv = Zbuf[idx];
        float zm = zv + half*kv;
        u16 h,l; splitw(zm,h,l); OutHi[idx]=h; OutLo[idx]=l;
        Zacc[idx] += dt3*kv;
      } else if constexpr (S == 2){
        float zv = Zbuf[idx];
        float zm = zv + dt*kv;
        u16 h,l; splitw(zm,h,l); OutHi[idx]=h; OutLo[idx]=l;
        Zacc[idx] += dt3*kv;
      } else {
        float zn = Zacc[idx] + dt6*kv;
        Zbuf[idx] = zn;                         // z (== d_out)
        u16 h,l; splitw(zn,h,l); OutHi[idx]=h; OutLo[idx]=l;
      }
    }
  }
}

extern "C" void kernel_launch(void* const* d_in, const int* in_sizes, int n_in,
                              void* d_out, int out_size, void* d_ws, size_t ws_size,
                              hipStream_t stream)
{
  (void)in_sizes; (void)n_in; (void)out_size; (void)ws_size;
  const float* z_init = (const float*)d_in[0];
  const float* tvec   = (const float*)d_in[1];
  const float* W1     = (const float*)d_in[2];
  const float* b1     = (const float*)d_in[3];
  const float* wt     = (const float*)d_in[4];
  const float* W2     = (const float*)d_in[5];
  const float* b2     = (const float*)d_in[6];
  float* z = (float*)d_out;                    // fp32 master state lives in d_out

  char* p = (char*)d_ws;
  const size_t EL = 512*1024;
  u16* zh  = (u16*)p; p += EL*2;
  u16* zl  = (u16*)p; p += EL*2;
  u16* zmh = (u16*)p; p += EL*2;
  u16* zml = (u16*)p; p += EL*2;
  u16* hh  = (u16*)p; p += EL*2;
  u16* hl  = (u16*)p; p += EL*2;
  float* zacc = (float*)p; p += EL*4;
  u16* W1h = (u16*)p; p += (size_t)1024*1024*2;
  u16* W1l = (u16*)p; p += (size_t)1024*1024*2;
  u16* W2h = (u16*)p; p += (size_t)1024*1024*2;
  u16* W2l = (u16*)p; p += (size_t)1024*1024*2;

  prep_weights<<<dim3(32,32),256,0,stream>>>(W1, W1h, W1l);
  prep_weights<<<dim3(32,32),256,0,stream>>>(W2, W2h, W2l);
  init_z<<<2048,256,0,stream>>>(z_init, z, zh, zl);

  for (int step=0; step<32; ++step){
    for (int s=0; s<4; ++s){
      const u16* ah = (s==0)? zh : zmh;
      const u16* al = (s==0)? zl : zml;
      fused_gemm<0><<<NGRID,BDIM,0,stream>>>(ah, al, W1h, W1l, b1, wt, tvec, step, s,
                                             hh, hl, nullptr, nullptr);
      u16* oh = (s==3)? zh : zmh;
      u16* ol = (s==3)? zl : zml;
      switch (s){
        case 0: fused_gemm<1><<<NGRID,BDIM,0,stream>>>(hh, hl, W2h, W2l, b2, nullptr, tvec, step, s, oh, ol, z, zacc); break;
        case 1: fused_gemm<2><<<NGRID,BDIM,0,stream>>>(hh, hl, W2h, W2l, b2, nullptr, tvec, step, s, oh, ol, z, zacc); break;
        case 2: fused_gemm<3><<<NGRID,BDIM,0,stream>>>(hh, hl, W2h, W2l, b2, nullptr, tvec, step, s, oh, ol, z, zacc); break;
        case 3: fused_gemm<4><<<NGRID,BDIM,0,stream>>>(hh, hl, W2h, W2l, b2, nullptr, tvec, step, s, oh, ol, z, zacc); break;
      }
    }
  }
}